// Round 18
// baseline (356.366 us; speedup 1.0000x reference)
//
#include <hip/hip_runtime.h>
#include <hip/hip_fp16.h>

#define F_IN 35
#define F_OUT 5
#define HID 100
#define BSH 8              // 256 node-ids per bucket
#define BMSK 255
#define MAXB 512           // max buckets (requires N <= 131072)
#define NBLK 128           // passB sort blocks per direction
#define CAPB 5120          // flat-cache coverage (mean bucket ~4096, +16 sigma)
#define KMAX 20            // CAPB / 256 threads

// 15-bit relative float for w in (0,1]: 4-bit exp, 11-bit mantissa.
__device__ __forceinline__ unsigned qenc(float w) {
  unsigned b = __float_as_uint(w);
  int e = 127 - (int)((b >> 23) & 0xFF);
  unsigned m = (b >> 12) & 0x7FFu;
  if (e < 0) { e = 0; m = 0; }
  if (e > 15) { e = 15; m = 0; }
  return ((unsigned)e << 11) | m;
}
__device__ __forceinline__ float qdec(unsigned q) {
  return __uint_as_float(((127u - (q >> 11)) << 23) | ((q & 0x7FFu) << 12));
}

__device__ __forceinline__ float2 uph2(unsigned u) {
  __half2 h = *reinterpret_cast<const __half2*>(&u);
  return __half22float2(h);
}
__device__ __forceinline__ unsigned pkh2(float a, float b) {
  __half2 h = __floats2half2_rn(a, b);
  return *reinterpret_cast<const unsigned*>(&h);
}

// Non-temporal LOADS only (edge lists, staged/adjacency streams). NT STORES
// forbidden (round-7: 6x write amplification on strided stores).
__device__ __forceinline__ int ntli(const int* p) {
  return __builtin_nontemporal_load(p);
}
__device__ __forceinline__ float ntlf(const float* p) {
  return __builtin_nontemporal_load(p);
}
__device__ __forceinline__ long long ntll(const long long* p) {
  return __builtin_nontemporal_load(p);
}
__device__ __forceinline__ void ntsf(float* p, float v) {
  __builtin_nontemporal_store(v, p);   // ONLY for coalesced final output
}

// 4-way split dot product: breaks the serial FMA chain (4x ILP).
__device__ __forceinline__ float dot4(const float* __restrict__ a,
                                      const float* __restrict__ b, int n,
                                      float init) {
  float s0 = init, s1 = 0.f, s2 = 0.f, s3 = 0.f;
  int n4 = n & ~3;
  #pragma unroll
  for (int i = 0; i < 40; i += 4) {
    if (i >= n4) break;
    s0 = fmaf(a[i], b[i], s0);
    s1 = fmaf(a[i + 1], b[i + 1], s1);
    s2 = fmaf(a[i + 2], b[i + 2], s2);
    s3 = fmaf(a[i + 3], b[i + 3], s3);
  }
  for (int i = n4; i < n; i++) s0 = fmaf(a[i], b[i], s0);
  return (s0 + s1) + (s2 + s3);
}

// ---------------------------------------------------------------------------
// Weight prep — all nodeA weights TRANSPOSED so per-wave-uniform rows are
// CONTIGUOUS (batched s_loads). W1t[100][35]; WpackAt[50][40];
// WpackCxt[25][35]; WpackCh[5][25].
// Column maps: A: 0-4 Dz, 5-9 Dr, 10-14 Fz1, 15-19 Fr1, 20-24 Fz2,
// 25-29 Fr2, 30-34 Bz1, 35-39 Br1, 40-44 Bz2, 45-49 Br2.
// C: 0-4 Dh, 5-9 Fh1, 10-14 Fh2, 15-19 Bh1, 20-24 Bh2.
// ---------------------------------------------------------------------------
__global__ __launch_bounds__(256) void prep_weights(
    const float* __restrict__ Wz, const float* __restrict__ Wr,
    const float* __restrict__ Wh, const float* __restrict__ W1,
    float* __restrict__ W1t, float* __restrict__ WpackAt,
    float* __restrict__ WpackCxt, float* __restrict__ WpackCh) {
  int t = blockIdx.x * blockDim.x + threadIdx.x;
  auto W = [&](const float* Wp, int d, int k, int i, int o) {
    return Wp[((d * 3 + k) * 40 + i) * 5 + o];
  };
  auto wa = [&](int i, int c) -> float {
    if (c < 5)  return W(Wz,0,0,i,c)+W(Wz,1,0,i,c)-W(Wz,0,2,i,c)-W(Wz,1,2,i,c);
    if (c < 10) return W(Wr,0,0,i,c-5)+W(Wr,1,0,i,c-5)-W(Wr,0,2,i,c-5)-W(Wr,1,2,i,c-5);
    if (c < 15) return W(Wz,0,1,i,c-10);
    if (c < 20) return W(Wr,0,1,i,c-15);
    if (c < 25) return W(Wz,0,2,i,c-20);
    if (c < 30) return W(Wr,0,2,i,c-25);
    if (c < 35) return W(Wz,1,1,i,c-30);
    if (c < 40) return W(Wr,1,1,i,c-35);
    if (c < 45) return W(Wz,1,2,i,c-40);
    return W(Wr,1,2,i,c-45);
  };
  auto wc = [&](int i, int c) -> float {
    if (c < 5)  return W(Wh,0,0,i,c)+W(Wh,1,0,i,c)-W(Wh,0,2,i,c)-W(Wh,1,2,i,c);
    if (c < 10) return W(Wh,0,1,i,c-5);
    if (c < 15) return W(Wh,0,2,i,c-10);
    if (c < 20) return W(Wh,1,1,i,c-15);
    return W(Wh,1,2,i,c-20);
  };
  if (t < 3500) {                       // W1t[hh][i]
    int hh = t / 35, i = t % 35;
    W1t[t] = W1[i * HID + hh];
  } else if (t < 5500) {                // WpackAt[c][i]
    int u = t - 3500; int c = u / 40, i = u % 40;
    WpackAt[u] = wa(i, c);
  } else if (t < 6375) {                // WpackCxt[c][i], i<35
    int u = t - 5500; int c = u / 35, i = u % 35;
    WpackCxt[u] = wc(i, c);
  } else if (t < 6500) {                // WpackCh[o][c] = wc(35+o, c)
    int u = t - 6375; int o = u / 25, c = u % 25;
    WpackCh[u] = wc(F_IN + o, c);
  }
}

// ---------------------------------------------------------------------------
// Build 1 (passB): LOCAL bucket sort (block-local write window).
// Item: int2{ other | keylow<<17 , 15-bit qweight }.
// ---------------------------------------------------------------------------
__global__ __launch_bounds__(1024) void passB_kernel(
    const int* __restrict__ ei, const float* __restrict__ w,
    int2* __restrict__ staged_f, int2* __restrict__ staged_b,
    int* __restrict__ lomat, int E) {
  __shared__ int hh[MAXB], sc[MAXB], cc[MAXB];
  int dir = blockIdx.y;               // 0: fwd (key=dst), 1: bwd (key=src)
  int j = blockIdx.x;
  int tid = threadIdx.x;
  for (int k = tid; k < MAXB; k += blockDim.x) { hh[k] = 0; cc[k] = 0; }
  __syncthreads();
  size_t c0 = (size_t)j * E / NBLK;
  size_t c1 = (size_t)(j + 1) * E / NBLK;
  const int* keyc = dir ? ei : ei + E;
  const int* othc = dir ? ei + E : ei;
  int2* staged = dir ? staged_b : staged_f;
  int* lom = lomat + ((size_t)dir * NBLK + j) * (MAXB + 1);
  for (size_t e = c0 + tid; e < c1; e += blockDim.x) {
    int key = ntli(keyc + e);
    atomicAdd(&hh[key >> BSH], 1);
  }
  __syncthreads();
  if (tid < MAXB) sc[tid] = hh[tid];
  __syncthreads();
  for (int off = 1; off < MAXB; off <<= 1) {
    int a = (tid >= off && tid < MAXB) ? sc[tid - off] : 0;
    __syncthreads();
    if (tid < MAXB) sc[tid] += a;
    __syncthreads();
  }
  if (tid < MAXB) {
    int lo = sc[tid] - hh[tid];
    lom[tid] = lo;
    hh[tid] = lo;
  }
  if (tid == 0) lom[MAXB] = (int)(c1 - c0);
  __syncthreads();
  for (size_t e = c0 + tid; e < c1; e += blockDim.x) {
    int key = ntli(keyc + e);
    int oth = ntli(othc + e);
    unsigned q = qenc(ntlf(w + e));
    int b = key >> BSH;
    int p = hh[b] + atomicAdd(&cc[b], 1);
    staged[c0 + p] = make_int2(oth | ((key & BMSK) << 17), (int)q);
  }
}

// ---------------------------------------------------------------------------
// Build 2: bucket bases = column sums of lomat count-diffs + exclusive scan.
// ---------------------------------------------------------------------------
__global__ __launch_bounds__(512) void scanb2_kernel(
    const int* __restrict__ lomat,
    int* __restrict__ bbase_f, int* __restrict__ bbase_b,
    int* __restrict__ rs_f, int* __restrict__ rs_b,
    int nbuck, int N, int E) {
  __shared__ int s0[MAXB], s1[MAXB];
  int t = threadIdx.x;
  int cf = 0, cb = 0;
  if (t < nbuck) {
    for (int j = 0; j < NBLK; j++) {
      const int* lf = lomat + (size_t)j * (MAXB + 1);
      const int* lb = lomat + ((size_t)NBLK + j) * (MAXB + 1);
      cf += lf[t + 1] - lf[t];
      cb += lb[t + 1] - lb[t];
    }
  }
  s0[t] = cf; s1[t] = cb;
  __syncthreads();
  for (int off = 1; off < MAXB; off <<= 1) {
    int a = (t >= off) ? s0[t - off] : 0;
    int b = (t >= off) ? s1[t - off] : 0;
    __syncthreads();
    s0[t] += a; s1[t] += b;
    __syncthreads();
  }
  bbase_f[t + 1] = s0[t];
  bbase_b[t + 1] = s1[t];
  if (t == 0) { bbase_f[0] = 0; bbase_b[0] = 0; rs_f[N] = E; rs_b[N] = E; }
}

// ---------------------------------------------------------------------------
// Build 3 (passC): per-bucket CSR finalize, FLAT-INDEXED + SINGLE READ:
// - lbase[129] scan over run lengths; run_of[p] byte table maps positions
//   to runs in O(1)
// - pass 1: flat coalesced loop, items cached in statically-indexed
//   registers (KMAX=20 covers CAPB=5120 >> mean 4096)
// - pass 2: pure register replay (zero global reads); tail >CAPB binary-
//   searches lbase (correctness fallback, never taken for this input)
// dir0 (fwd, keyed by dst) -> inv_in; dir1 (bwd, keyed by src) -> inv_out.
// ---------------------------------------------------------------------------
__global__ __launch_bounds__(256) void passC_kernel(
    const int2* __restrict__ staged_f, const int2* __restrict__ staged_b,
    const int* __restrict__ lomat,
    const int* __restrict__ bbase_f, const int* __restrict__ bbase_b,
    int* __restrict__ adj_f, int* __restrict__ adj_b,
    int* __restrict__ rs_f, int* __restrict__ rs_b,
    float* __restrict__ inv_in, float* __restrict__ inv_out, int N, int E) {
  int dir = blockIdx.y;
  const long long* staged =
      (const long long*)(dir ? staged_b : staged_f);
  const int* lomd = lomat + (size_t)dir * NBLK * (MAXB + 1);
  const int* bbase = dir ? bbase_b : bbase_f;
  int* adj = dir ? adj_b : adj_f;
  int* rs  = dir ? rs_b : rs_f;
  float* inv = dir ? inv_out : inv_in;
  int b = blockIdx.x;
  int base = bbase[b];
  __shared__ int cnt[256]; __shared__ float wsum[256];
  __shared__ int loc[256]; __shared__ int cur[256];
  __shared__ int lbase[NBLK + 1];
  __shared__ int lo0s[NBLK];
  __shared__ int cjs[NBLK];
  __shared__ unsigned char run_of[CAPB];
  int tid = threadIdx.x;
  cnt[tid] = 0; wsum[tid] = 0.f; cur[tid] = 0;
  if (tid < NBLK) {
    const int* lj = lomd + (size_t)tid * (MAXB + 1);
    int lo0 = lj[b], lo1 = lj[b + 1];
    lo0s[tid] = lo0;
    lbase[tid] = lo1 - lo0;
    cjs[tid] = (int)((size_t)tid * E / NBLK);
  }
  __syncthreads();
  // inclusive scan over 128 run lengths
  for (int off = 1; off < NBLK; off <<= 1) {
    int v = (tid < NBLK && tid >= off) ? lbase[tid - off] : 0;
    __syncthreads();
    if (tid < NBLK) lbase[tid] += v;
    __syncthreads();
  }
  int incl = (tid < NBLK) ? lbase[tid] : 0;
  __syncthreads();
  if (tid < NBLK) lbase[tid + 1] = incl;
  if (tid == 0) lbase[0] = 0;
  __syncthreads();
  int total = lbase[NBLK];
  // fill run_of (one thread per run)
  if (tid < NBLK) {
    int p0 = lbase[tid], p1 = lbase[tid + 1];
    int pe = min(p1, CAPB);
    for (int p = p0; p < pe; p++) run_of[p] = (unsigned char)tid;
  }
  __syncthreads();

  // pass 1: flat coalesced loop, cache items in registers
  long long items[KMAX];
  #pragma unroll
  for (int k = 0; k < KMAX; k++) {
    int p = tid + (k << 8);
    if (p < total && p < CAPB) {
      int j = run_of[p];
      int idx = cjs[j] + lo0s[j] + (p - lbase[j]);
      long long it = ntll(staged + idx);
      items[k] = it;
      int idv = (int)(unsigned)(it & 0xFFFFFFFFll);
      unsigned q = (unsigned)((unsigned long long)it >> 32);
      int nl = (idv >> 17) & BMSK;
      atomicAdd(&cnt[nl], 1);
      atomicAdd(&wsum[nl], qdec(q));
    }
  }
  // tail (p >= CAPB): binary search (correctness fallback)
  for (int p = CAPB + tid; p < total; p += 256) {
    int loJ = 0, hiJ = NBLK;
    while (hiJ - loJ > 1) {
      int mid = (loJ + hiJ) >> 1;
      if (lbase[mid] <= p) loJ = mid; else hiJ = mid;
    }
    long long it = ntll(staged + cjs[loJ] + lo0s[loJ] + (p - lbase[loJ]));
    int idv = (int)(unsigned)(it & 0xFFFFFFFFll);
    unsigned q = (unsigned)((unsigned long long)it >> 32);
    int nl = (idv >> 17) & BMSK;
    atomicAdd(&cnt[nl], 1);
    atomicAdd(&wsum[nl], qdec(q));
  }
  __syncthreads();

  // per-node exclusive scan (256 nodes) -> rowstarts + inv degrees
  int v = cnt[tid];
  loc[tid] = v;
  __syncthreads();
  for (int off = 1; off < 256; off <<= 1) {
    int a = (tid >= off) ? loc[tid - off] : 0;
    __syncthreads();
    loc[tid] += a;
    __syncthreads();
  }
  int excl = loc[tid] - v;
  int node = (b << BSH) + tid;
  if (node < N) {
    rs[node] = base + excl;
    inv[node] = 1.f / fmaxf(wsum[tid], 1e-12f);
  }
  __syncthreads();
  loc[tid] = excl;
  __syncthreads();

  // pass 2: register replay (no global reads)
  #pragma unroll
  for (int k = 0; k < KMAX; k++) {
    int p = tid + (k << 8);
    if (p < total && p < CAPB) {
      long long it = items[k];
      int idv = (int)(unsigned)(it & 0xFFFFFFFFll);
      int q = (int)((unsigned long long)it >> 32);
      int nl = (idv >> 17) & BMSK;
      int pos = base + loc[nl] + atomicAdd(&cur[nl], 1);
      adj[pos] = (idv & 0x1FFFF) | (q << 17);
    }
  }
  for (int p = CAPB + tid; p < total; p += 256) {
    int loJ = 0, hiJ = NBLK;
    while (hiJ - loJ > 1) {
      int mid = (loJ + hiJ) >> 1;
      if (lbase[mid] <= p) loJ = mid; else hiJ = mid;
    }
    long long it = ntll(staged + cjs[loJ] + lo0s[loJ] + (p - lbase[loJ]));
    int idv = (int)(unsigned)(it & 0xFFFFFFFFll);
    int q = (int)((unsigned long long)it >> 32);
    int nl = (idv >> 17) & BMSK;
    int pos = base + loc[nl] + atomicAdd(&cur[nl], 1);
    adj[pos] = (idv & 0x1FFFF) | (q << 17);
  }
}

// ---------------------------------------------------------------------------
// Output A: w_fwd = ew * inv_out[src]  (nt store OK: coalesced final output)
// ---------------------------------------------------------------------------
__global__ __launch_bounds__(256) void wfout_kernel(
    const int* __restrict__ ei, const float* __restrict__ ew,
    const float* __restrict__ inv_out, float* __restrict__ wf, int E) {
  for (int e = blockIdx.x * blockDim.x + threadIdx.x; e < E;
       e += gridDim.x * blockDim.x)
    ntsf(wf + e, ntlf(ew + e) * inv_out[ntli(ei + e)]);
}

// ---------------------------------------------------------------------------
// Node phase A: block = 4 waves = 64 nodes; wave-uniform weight indexing
// over TRANSPOSED weights. 4-WAY SPLIT ACCUMULATORS (dot4) break the serial
// FMA chains (round-17 PMC: VALUBusy 33% at 36% occupancy = ILP-starved).
// Emits fp16 PA (p1 gather input, pre-scaled) and fp16 accCx = x@WpackC[0:35].
// ---------------------------------------------------------------------------
__global__ __launch_bounds__(256) void nodeA_kernel(
    const float* __restrict__ x,
    const float* __restrict__ W1t, const float* __restrict__ b1,
    const float* __restrict__ W2, const float* __restrict__ b2,
    const float* __restrict__ bz, const float* __restrict__ br,
    const float* __restrict__ WpackAt, const float* __restrict__ WpackCxt,
    const float* __restrict__ inv_out, const float* __restrict__ inv_in,
    float* __restrict__ h1, float* __restrict__ accDz,
    float* __restrict__ accDr, __half* __restrict__ PA_f,
    __half* __restrict__ PA_b, __half* __restrict__ accCx, int N) {
  __shared__ float part[4][64][5];
  int tid = threadIdx.x;
  int lane = tid & 63;
  int q = __builtin_amdgcn_readfirstlane(tid >> 6);
  int n = blockIdx.x * 64 + lane;
  bool act = n < N;
  float xv[40];
  const float* xr = x + (size_t)n * F_IN;
  #pragma unroll
  for (int i = 0; i < F_IN; i++) xv[i] = act ? xr[i] : 0.f;

  float h5[5] = {0.f, 0.f, 0.f, 0.f, 0.f};
  int hbase = q * 25;
  for (int k = 0; k < 25; k++) {
    int hh = hbase + k;
    float a = dot4(xv, W1t + hh * F_IN, F_IN, b1[hh]);
    a = fmaxf(a, 0.f);
    #pragma unroll
    for (int o = 0; o < 5; o++) h5[o] = fmaf(a, W2[hh * 5 + o], h5[o]);
  }
  #pragma unroll
  for (int o = 0; o < 5; o++) part[q][lane][o] = h5[o];
  __syncthreads();
  #pragma unroll
  for (int o = 0; o < 5; o++) {
    h5[o] = part[0][lane][o] + part[1][lane][o] + part[2][lane][o] +
            part[3][lane][o] + b2[o];
    xv[F_IN + o] = h5[o];
  }
  if (!act) return;
  if (q == 0) {
    #pragma unroll
    for (int o = 0; o < 5; o++) h1[(size_t)n * 5 + o] = h5[o];
  }
  float sOut = inv_out[n], sIn = inv_in[n];
  // 75 columns: 0-49 WpackAt (XH), 50-74 WpackCxt (x only)
  int c0 = q * 19, c1 = min(c0 + 19, 75);
  for (int c = c0; c < c1; c++) {
    float a;
    if (c < 50) {
      a = dot4(xv, WpackAt + c * 40, 40, 0.f);
    } else {
      a = dot4(xv, WpackCxt + (c - 50) * F_IN, F_IN, 0.f);
    }
    if (c < 5)       accDz[(size_t)n * 5 + c] = a + bz[c];
    else if (c < 10) accDr[(size_t)n * 5 + (c - 5)] = a + br[c - 5];
    else if (c < 30) PA_f[(size_t)n * 20 + (c - 10)] = __float2half(a * sOut);
    else if (c < 50) PA_b[(size_t)n * 20 + (c - 30)] = __float2half(a * sIn);
    else             accCx[(size_t)n * 25 + (c - 50)] = __float2half(a);
  }
}

// ---------------------------------------------------------------------------
// P1: 1-hop fwd+bwd. DIR-PER-BLOCK. Paired lanes share (node,dir), 10-col
// halves. 4-wide BATCHED gather loop (overlaps 4 gather latencies).
// half0 -> Q1 fp32; half1 -> Q2 fp16 [N][12] (5+pad groups, pre-scaled).
// ---------------------------------------------------------------------------
__global__ __launch_bounds__(256) void p1_kernel(
    const int* __restrict__ rs_f, const int* __restrict__ rs_b,
    const int* __restrict__ adj_f, const int* __restrict__ adj_b,
    const __half* __restrict__ PA_f, const __half* __restrict__ PA_b,
    const float* __restrict__ inv_out, const float* __restrict__ inv_in,
    float* __restrict__ Q1_f, float* __restrict__ Q1_b,
    __half* __restrict__ Q2_f, __half* __restrict__ Q2_b, int N) {
  int dir = blockIdx.x & 1;
  int idx = (blockIdx.x >> 1) * 256 + threadIdx.x;
  if (idx >= 2 * N) return;
  int n = idx >> 1, half = idx & 1;
  const int* rs  = dir ? rs_b : rs_f;
  const int* adj = dir ? adj_b : adj_f;
  const __half* PA = dir ? PA_b : PA_f;
  int i0 = rs[n], i1 = rs[n + 1];
  float acc[10];
  #pragma unroll
  for (int c = 0; c < 10; c++) acc[c] = 0.f;
  int i = i0;
  for (; i + 4 <= i1; i += 4) {
    int a0 = ntli(adj + i),     a1 = ntli(adj + i + 1),
        a2 = ntli(adj + i + 2), a3 = ntli(adj + i + 3);
    const unsigned* r0 = (const unsigned*)(PA + (size_t)(a0 & 0x1FFFF) * 20) + half * 5;
    const unsigned* r1 = (const unsigned*)(PA + (size_t)(a1 & 0x1FFFF) * 20) + half * 5;
    const unsigned* r2 = (const unsigned*)(PA + (size_t)(a2 & 0x1FFFF) * 20) + half * 5;
    const unsigned* r3 = (const unsigned*)(PA + (size_t)(a3 & 0x1FFFF) * 20) + half * 5;
    unsigned u0[5], u1[5], u2[5], u3[5];
    #pragma unroll
    for (int k = 0; k < 5; k++) u0[k] = r0[k];
    #pragma unroll
    for (int k = 0; k < 5; k++) u1[k] = r1[k];
    #pragma unroll
    for (int k = 0; k < 5; k++) u2[k] = r2[k];
    #pragma unroll
    for (int k = 0; k < 5; k++) u3[k] = r3[k];
    float w0 = qdec(((unsigned)a0) >> 17), w1 = qdec(((unsigned)a1) >> 17),
          w2 = qdec(((unsigned)a2) >> 17), w3 = qdec(((unsigned)a3) >> 17);
    #pragma unroll
    for (int k = 0; k < 5; k++) {
      float2 f0 = uph2(u0[k]), f1 = uph2(u1[k]), f2 = uph2(u2[k]), f3 = uph2(u3[k]);
      acc[2*k]   = fmaf(w0, f0.x, acc[2*k]);   acc[2*k+1] = fmaf(w0, f0.y, acc[2*k+1]);
      acc[2*k]   = fmaf(w1, f1.x, acc[2*k]);   acc[2*k+1] = fmaf(w1, f1.y, acc[2*k+1]);
      acc[2*k]   = fmaf(w2, f2.x, acc[2*k]);   acc[2*k+1] = fmaf(w2, f2.y, acc[2*k+1]);
      acc[2*k]   = fmaf(w3, f3.x, acc[2*k]);   acc[2*k+1] = fmaf(w3, f3.y, acc[2*k+1]);
    }
  }
  for (; i < i1; i++) {
    int a = ntli(adj + i);
    float w = qdec(((unsigned)a) >> 17);
    const unsigned* row = (const unsigned*)(PA + (size_t)(a & 0x1FFFF) * 20) + half * 5;
    #pragma unroll
    for (int k = 0; k < 5; k++) {
      float2 f = uph2(row[k]);
      acc[2*k] = fmaf(w, f.x, acc[2*k]); acc[2*k+1] = fmaf(w, f.y, acc[2*k+1]);
    }
  }
  if (!half) {
    float* q = (dir ? Q1_b : Q1_f) + (size_t)n * 10;
    #pragma unroll
    for (int c = 0; c < 10; c++) q[c] = acc[c];
  } else {
    float sc = dir ? inv_in[n] : inv_out[n];
    unsigned* q = (unsigned*)((dir ? Q2_b : Q2_f) + (size_t)n * 12);
    q[0] = pkh2(acc[0] * sc, acc[1] * sc);
    q[1] = pkh2(acc[2] * sc, acc[3] * sc);
    q[2] = pkh2(acc[4] * sc, 0.f);
    q[3] = pkh2(acc[5] * sc, acc[6] * sc);
    q[4] = pkh2(acc[7] * sc, acc[8] * sc);
    q[5] = pkh2(acc[9] * sc, 0.f);
  }
}

// ---------------------------------------------------------------------------
// P2a: 2-hop gather, DIR-PER-BLOCK (single-dir Q2 = 2.88MB, L2-resident per
// XCD). Paired lanes = (node, group). 8-wide batched gather.
// Writes per-direction partials G[dir][N][10] fp32 (node-local).
// ---------------------------------------------------------------------------
__global__ __launch_bounds__(256) void p2a_kernel(
    const int* __restrict__ rs_f, const int* __restrict__ rs_b,
    const int* __restrict__ adj_f, const int* __restrict__ adj_b,
    const __half* __restrict__ Q2_f, const __half* __restrict__ Q2_b,
    float* __restrict__ G_f, float* __restrict__ G_b, int N) {
  int dir = blockIdx.x & 1;
  int idx = (blockIdx.x >> 1) * 256 + threadIdx.x;
  if (idx >= 2 * N) return;
  int n = idx >> 1, grp = idx & 1;
  const int* rs  = dir ? rs_b : rs_f;
  const int* adj = dir ? adj_b : adj_f;
  const __half* Q2 = dir ? Q2_b : Q2_f;
  int i0 = rs[n], i1 = rs[n + 1];
  float a[5];
  #pragma unroll
  for (int c = 0; c < 5; c++) a[c] = 0.f;
  int i = i0;
  for (; i + 8 <= i1; i += 8) {
    int e[8];
    #pragma unroll
    for (int k = 0; k < 8; k++) e[k] = ntli(adj + i + k);
    unsigned u[8][3];
    #pragma unroll
    for (int k = 0; k < 8; k++) {
      const unsigned* row =
          (const unsigned*)(Q2 + (size_t)(e[k] & 0x1FFFF) * 12) + grp * 3;
      u[k][0] = row[0]; u[k][1] = row[1]; u[k][2] = row[2];
    }
    #pragma unroll
    for (int k = 0; k < 8; k++) {
      float w = qdec(((unsigned)e[k]) >> 17);
      float2 f0 = uph2(u[k][0]), f1 = uph2(u[k][1]), f2 = uph2(u[k][2]);
      a[0] = fmaf(w, f0.x, a[0]); a[1] = fmaf(w, f0.y, a[1]);
      a[2] = fmaf(w, f1.x, a[2]); a[3] = fmaf(w, f1.y, a[3]);
      a[4] = fmaf(w, f2.x, a[4]);
    }
  }
  for (; i < i1; i++) {
    int e = ntli(adj + i);
    float w = qdec(((unsigned)e) >> 17);
    const unsigned* row =
        (const unsigned*)(Q2 + (size_t)(e & 0x1FFFF) * 12) + grp * 3;
    float2 f0 = uph2(row[0]), f1 = uph2(row[1]), f2 = uph2(row[2]);
    a[0] = fmaf(w, f0.x, a[0]); a[1] = fmaf(w, f0.y, a[1]);
    a[2] = fmaf(w, f1.x, a[2]); a[3] = fmaf(w, f1.y, a[3]);
    a[4] = fmaf(w, f2.x, a[4]);
  }
  float* g = (dir ? G_b : G_f) + (size_t)n * 10 + grp * 5;
  #pragma unroll
  for (int c = 0; c < 5; c++) g[c] = a[c];
}

// ---------------------------------------------------------------------------
// P2b: nodeB body (streaming only). zA/rA = G_f + G_b; gates; XHr epilogue
// (accCx precomputed; only the 5 h-rows via WpackCh). 2N threads, columns
// split 13/12 over lane pair.
// ---------------------------------------------------------------------------
__global__ __launch_bounds__(256) void p2b_kernel(
    const float* __restrict__ G_f, const float* __restrict__ G_b,
    const float* __restrict__ Q1_f, const float* __restrict__ Q1_b,
    const float* __restrict__ accDz, const float* __restrict__ accDr,
    const __half* __restrict__ accCx, const float* __restrict__ h1,
    const float* __restrict__ bh, const float* __restrict__ WpackCh,
    const float* __restrict__ inv_out, const float* __restrict__ inv_in,
    float* __restrict__ Zg, float* __restrict__ accDh,
    __half* __restrict__ PH_f, __half* __restrict__ PH_b, int N) {
  int t = blockIdx.x * blockDim.x + threadIdx.x;
  int n = t >> 1, l = t & 1;
  if (n >= N) return;
  float r[5], zv[5];
  #pragma unroll
  for (int o = 0; o < 5; o++) {
    float zA = G_f[(size_t)n * 10 + o] + G_b[(size_t)n * 10 + o];
    float rA = G_f[(size_t)n * 10 + 5 + o] + G_b[(size_t)n * 10 + 5 + o];
    float zp = accDz[(size_t)n * 5 + o] + Q1_f[(size_t)n * 10 + o] +
               Q1_b[(size_t)n * 10 + o] + 2.f * zA;
    float rp = accDr[(size_t)n * 5 + o] + Q1_f[(size_t)n * 10 + 5 + o] +
               Q1_b[(size_t)n * 10 + 5 + o] + 2.f * rA;
    zv[o] = 1.f / (1.f + __expf(-zp));
    r[o]  = 1.f / (1.f + __expf(-rp));
  }
  if (l == 0) {
    #pragma unroll
    for (int o = 0; o < 5; o++) Zg[(size_t)n * 5 + o] = zv[o];
  }
  float hr[5];
  #pragma unroll
  for (int o = 0; o < 5; o++) hr[o] = h1[(size_t)n * 5 + o] * r[o];

  float sOut = inv_out[n], sIn = inv_in[n];
  int c0 = l ? 13 : 0, c1 = l ? 25 : 13;
  for (int c = c0; c < c1; c++) {
    float acc = __half2float(accCx[(size_t)n * 25 + c]);
    #pragma unroll
    for (int o = 0; o < 5; o++) acc = fmaf(hr[o], WpackCh[o * 25 + c], acc);
    if (c < 5)       accDh[(size_t)n * 5 + c] = acc + bh[c];
    else if (c < 10) PH_f[(size_t)n * 12 + (c - 5)] = __float2half(acc * sOut);
    else if (c < 15) PH_f[(size_t)n * 12 + 6 + (c - 10)] = __float2half(acc * sOut);
    else if (c < 20) PH_b[(size_t)n * 12 + (c - 15)] = __float2half(acc * sIn);
    else             PH_b[(size_t)n * 12 + 6 + (c - 20)] = __float2half(acc * sIn);
  }
}

// ---------------------------------------------------------------------------
// P3: 1-hop h, DIR-PER-BLOCK; paired-lane split over PH's two 5-col groups.
// 8-wide batched gather. (h0-4 -> Q1h fp32; h6-10 -> Q2h fp16 pre-scaled.)
// ---------------------------------------------------------------------------
__global__ __launch_bounds__(256) void p3_kernel(
    const int* __restrict__ rs_f, const int* __restrict__ rs_b,
    const int* __restrict__ adj_f, const int* __restrict__ adj_b,
    const __half* __restrict__ PH_f, const __half* __restrict__ PH_b,
    const float* __restrict__ inv_out, const float* __restrict__ inv_in,
    float* __restrict__ Q1h_f, float* __restrict__ Q1h_b,
    __half* __restrict__ Q2h_f, __half* __restrict__ Q2h_b, int N) {
  int dir = blockIdx.x & 1;
  int idx = (blockIdx.x >> 1) * 256 + threadIdx.x;
  if (idx >= 2 * N) return;
  int n = idx >> 1, half = idx & 1;
  const int* rs  = dir ? rs_b : rs_f;
  const int* adj = dir ? adj_b : adj_f;
  const __half* PH = dir ? PH_b : PH_f;
  int i0 = rs[n], i1 = rs[n + 1];
  float acc[5];
  #pragma unroll
  for (int c = 0; c < 5; c++) acc[c] = 0.f;
  int i = i0;
  for (; i + 8 <= i1; i += 8) {
    int e[8];
    #pragma unroll
    for (int k = 0; k < 8; k++) e[k] = ntli(adj + i + k);
    unsigned u[8][3];
    #pragma unroll
    for (int k = 0; k < 8; k++) {
      const unsigned* row =
          (const unsigned*)(PH + (size_t)(e[k] & 0x1FFFF) * 12) + half * 3;
      u[k][0] = row[0]; u[k][1] = row[1]; u[k][2] = row[2];
    }
    #pragma unroll
    for (int k = 0; k < 8; k++) {
      float w = qdec(((unsigned)e[k]) >> 17);
      float2 f0 = uph2(u[k][0]), f1 = uph2(u[k][1]), f2 = uph2(u[k][2]);
      acc[0] = fmaf(w, f0.x, acc[0]); acc[1] = fmaf(w, f0.y, acc[1]);
      acc[2] = fmaf(w, f1.x, acc[2]); acc[3] = fmaf(w, f1.y, acc[3]);
      acc[4] = fmaf(w, f2.x, acc[4]);
    }
  }
  for (; i < i1; i++) {
    int a = ntli(adj + i);
    float w = qdec(((unsigned)a) >> 17);
    const unsigned* row =
        (const unsigned*)(PH + (size_t)(a & 0x1FFFF) * 12) + half * 3;
    float2 f0 = uph2(row[0]), f1 = uph2(row[1]), f2 = uph2(row[2]);
    acc[0] = fmaf(w, f0.x, acc[0]); acc[1] = fmaf(w, f0.y, acc[1]);
    acc[2] = fmaf(w, f1.x, acc[2]); acc[3] = fmaf(w, f1.y, acc[3]);
    acc[4] = fmaf(w, f2.x, acc[4]);
  }
  if (!half) {
    float* q = (dir ? Q1h_b : Q1h_f) + (size_t)n * 5;
    #pragma unroll
    for (int c = 0; c < 5; c++) q[c] = acc[c];
  } else {
    float sc = dir ? inv_in[n] : inv_out[n];
    unsigned* q = (unsigned*)((dir ? Q2h_b : Q2h_f) + (size_t)n * 8);
    q[0] = pkh2(acc[0] * sc, acc[1] * sc);
    q[1] = pkh2(acc[2] * sc, acc[3] * sc);
    q[2] = pkh2(acc[4] * sc, 0.f);
  }
}

// ---------------------------------------------------------------------------
// P4: 2-hop h gather (fp16 Q2h, lane dir-split, 8-wide batched) + nodeC -> y.
// ---------------------------------------------------------------------------
__global__ __launch_bounds__(256) void p4_kernel(
    const int* __restrict__ rs_f, const int* __restrict__ rs_b,
    const int* __restrict__ adj_f, const int* __restrict__ adj_b,
    const __half* __restrict__ Q2h_f, const __half* __restrict__ Q2h_b,
    const float* __restrict__ Q1h_f, const float* __restrict__ Q1h_b,
    const float* __restrict__ accDh, const float* __restrict__ Zg,
    const float* __restrict__ h1, const float* __restrict__ Wl,
    const float* __restrict__ bl, float* __restrict__ y, int N) {
  int t = blockIdx.x * blockDim.x + threadIdx.x;
  int n = t >> 1, l = t & 1;
  if (n >= N) return;
  const int* rs  = l ? rs_b : rs_f;
  const int* adj = l ? adj_b : adj_f;
  const __half* Q2h = l ? Q2h_b : Q2h_f;
  float a[5];
  #pragma unroll
  for (int c = 0; c < 5; c++) a[c] = 0.f;
  int i0 = rs[n], i1 = rs[n + 1];
  int i = i0;
  for (; i + 8 <= i1; i += 8) {
    int e[8];
    #pragma unroll
    for (int k = 0; k < 8; k++) e[k] = ntli(adj + i + k);
    unsigned u[8][3];
    #pragma unroll
    for (int k = 0; k < 8; k++) {
      const unsigned* row = (const unsigned*)(Q2h + (size_t)(e[k] & 0x1FFFF) * 8);
      u[k][0] = row[0]; u[k][1] = row[1]; u[k][2] = row[2];
    }
    #pragma unroll
    for (int k = 0; k < 8; k++) {
      float w = qdec(((unsigned)e[k]) >> 17);
      float2 f0 = uph2(u[k][0]), f1 = uph2(u[k][1]), f2 = uph2(u[k][2]);
      a[0] = fmaf(w, f0.x, a[0]); a[1] = fmaf(w, f0.y, a[1]);
      a[2] = fmaf(w, f1.x, a[2]); a[3] = fmaf(w, f1.y, a[3]);
      a[4] = fmaf(w, f2.x, a[4]);
    }
  }
  for (; i < i1; i++) {
    int e = ntli(adj + i);
    float w = qdec(((unsigned)e) >> 17);
    const unsigned* row = (const unsigned*)(Q2h + (size_t)(e & 0x1FFFF) * 8);
    float2 f0 = uph2(row[0]), f1 = uph2(row[1]), f2 = uph2(row[2]);
    a[0] = fmaf(w, f0.x, a[0]); a[1] = fmaf(w, f0.y, a[1]);
    a[2] = fmaf(w, f1.x, a[2]); a[3] = fmaf(w, f1.y, a[3]);
    a[4] = fmaf(w, f2.x, a[4]);
  }
  #pragma unroll
  for (int c = 0; c < 5; c++) a[c] += __shfl_xor(a[c], 1);
  if (l) return;
  float acc = bl[0];
  #pragma unroll
  for (int o = 0; o < 5; o++) {
    float pre = accDh[(size_t)n * 5 + o] + Q1h_f[(size_t)n * 5 + o] +
                Q1h_b[(size_t)n * 5 + o] + 2.f * a[o];
    float ht = tanhf(pre);
    float z = Zg[(size_t)n * 5 + o];
    float H = z * h1[(size_t)n * 5 + o] + (1.f - z) * ht;
    acc += fmaxf(H, 0.f) * Wl[o];
  }
  y[n] = acc;
}

// ---------------------------------------------------------------------------
extern "C" void kernel_launch(void* const* d_in, const int* in_sizes, int n_in,
                              void* d_out, int out_size, void* d_ws, size_t ws_size,
                              hipStream_t stream) {
  const float* x  = (const float*)d_in[0];
  const int*   ei = (const int*)d_in[1];
  const float* ew = (const float*)d_in[2];
  const float* W1 = (const float*)d_in[3];
  const float* b1 = (const float*)d_in[4];
  const float* W2 = (const float*)d_in[5];
  const float* b2 = (const float*)d_in[6];
  const float* Wz = (const float*)d_in[7];
  const float* bz = (const float*)d_in[8];
  const float* Wr = (const float*)d_in[9];
  const float* br = (const float*)d_in[10];
  const float* Wh = (const float*)d_in[11];
  const float* bh = (const float*)d_in[12];
  const float* Wl = (const float*)d_in[13];
  const float* bl = (const float*)d_in[14];

  const int N = in_sizes[0] / F_IN;
  const int E = in_sizes[2];
  const int nbuck = ((N - 1) >> BSH) + 1;   // N <= 131072 assumed

  float* out = (float*)d_out;
  float* y_out  = out;          // [N]
  float* wf_out = out + N;      // [E]  == output A

  // Workspace layout (4-byte words; 8B alignment maintained for packed loads)
  float* W = (float*)d_ws;
  size_t o = 0;
  int* bbase_f = (int*)(W + o); o += MAXB + 2;
  int* bbase_b = (int*)(W + o); o += MAXB + 2;
  int* lomat   = (int*)(W + o); o += (size_t)2 * NBLK * (MAXB + 1);
  int* rs_f    = (int*)(W + o); o += (size_t)N + 1;
  int* rs_b    = (int*)(W + o); o += (size_t)N + 1;
  float* inv_out = W + o; o += N;
  float* inv_in  = W + o; o += N;
  int* adj_f   = (int*)(W + o); o += (size_t)E;
  int* adj_b   = (int*)(W + o); o += (size_t)E;
  float* h1    = W + o; o += (size_t)5 * N;
  float* accDz = W + o; o += (size_t)5 * N;
  float* accDr = W + o; o += (size_t)5 * N;
  float* accDh = W + o; o += (size_t)5 * N;
  float* Zg    = W + o; o += (size_t)5 * N;
  __half* accCx = (__half*)(W + o); o += (size_t)13 * N;  // [N][25] fp16
  o = (o + 1) & ~(size_t)1;                 // 8B align
  size_t prop0 = o;                         // staged aliases from here
  __half* PA_f = (__half*)(W + o); o += (size_t)10 * N;   // [N][20] fp16
  __half* PA_b = (__half*)(W + o); o += (size_t)10 * N;
  float* Q1_f  = W + o; o += (size_t)10 * N;              // [N][10] fp32
  float* Q1_b  = W + o; o += (size_t)10 * N;
  __half* Q2_f = (__half*)(W + o); o += (size_t)6 * N;    // [N][12] fp16
  __half* Q2_b = (__half*)(W + o); o += (size_t)6 * N;
  __half* PH_f = (__half*)(W + o); o += (size_t)6 * N;    // [N][12] fp16
  __half* PH_b = (__half*)(W + o); o += (size_t)6 * N;
  float* Q1h_f = W + o; o += (size_t)5 * N;               // [N][5] fp32
  float* Q1h_b = W + o; o += (size_t)5 * N;
  o = (o + 1) & ~(size_t)1;
  __half* Q2h_f = (__half*)(W + o); o += (size_t)4 * N;   // [N][8] fp16
  __half* Q2h_b = (__half*)(W + o); o += (size_t)4 * N;
  float* G_f   = W + o; o += (size_t)10 * N;              // [N][10] fp32
  float* G_b   = W + o; o += (size_t)10 * N;
  float* W1t     = W + o; o += 3500;                      // [100][35]
  float* WpackAt = W + o; o += 2000;                      // [50][40]
  float* WpackCxt = W + o; o += 875;                      // [25][35]
  float* WpackCh  = W + o; o += 125;                      // [5][25]

  // staged scratch aliases the prop region (consumed by passC before nodeA
  // writes anything there); needs 4E words <= prop-region words (~102N).
  int2* staged_f = (int2*)(W + prop0);
  int2* staged_b = staged_f + E;

  const int NB2 = (2 * N + 255) / 256;
  const int NBd = 2 * ((2 * N + 255) / 256);   // dir-per-block grids
  const int NBn = (N + 63) / 64;

  // 1. packed/transposed weights (6500 work items)
  prep_weights<<<26, 256, 0, stream>>>(Wz, Wr, Wh, W1,
                                       W1t, WpackAt, WpackCxt, WpackCh);

  // 2. CSR build: local sort -> bucket-base scan -> per-bucket finalize
  passB_kernel<<<dim3(NBLK, 2), 1024, 0, stream>>>(ei, ew, staged_f, staged_b,
                                                   lomat, E);
  scanb2_kernel<<<1, MAXB, 0, stream>>>(lomat, bbase_f, bbase_b,
                                        rs_f, rs_b, nbuck, N, E);
  passC_kernel<<<dim3(nbuck, 2), 256, 0, stream>>>(
      staged_f, staged_b, lomat, bbase_f, bbase_b, adj_f, adj_b,
      rs_f, rs_b, inv_in, inv_out, N, E);
  wfout_kernel<<<1024, 256, 0, stream>>>(ei, ew, inv_out, wf_out, E);

  // 3. node phase A (transposed weights, 4-way split accumulators)
  nodeA_kernel<<<NBn, 256, 0, stream>>>(x, W1t, b1, W2, b2, bz, br, WpackAt,
                                        WpackCxt, inv_out, inv_in,
                                        h1, accDz, accDr, PA_f, PA_b,
                                        accCx, N);

  // 4. fused propagation + gate phases
  p1_kernel<<<NBd, 256, 0, stream>>>(rs_f, rs_b, adj_f, adj_b, PA_f, PA_b,
                                     inv_out, inv_in, Q1_f, Q1_b, Q2_f, Q2_b, N);
  p2a_kernel<<<NBd, 256, 0, stream>>>(rs_f, rs_b, adj_f, adj_b, Q2_f, Q2_b,
                                      G_f, G_b, N);
  p2b_kernel<<<NB2, 256, 0, stream>>>(G_f, G_b, Q1_f, Q1_b, accDz, accDr,
                                      accCx, h1, bh, WpackCh, inv_out, inv_in,
                                      Zg, accDh, PH_f, PH_b, N);
  p3_kernel<<<NBd, 256, 0, stream>>>(rs_f, rs_b, adj_f, adj_b, PH_f, PH_b,
                                     inv_out, inv_in, Q1h_f, Q1h_b,
                                     Q2h_f, Q2h_b, N);
  p4_kernel<<<NB2, 256, 0, stream>>>(rs_f, rs_b, adj_f, adj_b, Q2h_f, Q2h_b,
                                     Q1h_f, Q1h_b, accDh, Zg, h1, Wl, bl,
                                     y_out, N);
}

// Round 19
// 347.801 us; speedup vs baseline: 1.0246x; 1.0246x over previous
//
#include <hip/hip_runtime.h>
#include <hip/hip_fp16.h>

#define F_IN 35
#define F_OUT 5
#define HID 100
#define BSH 8              // 256 node-ids per bucket
#define BMSK 255
#define MAXB 512           // max buckets (requires N <= 131072)
#define NBLK 128           // passB sort blocks per direction
#define CAPB 5120          // flat-cache coverage (mean bucket ~4096, +16 sigma)
#define KMAX 20            // CAPB / 256 threads

// 15-bit relative float for w in (0,1]: 4-bit exp, 11-bit mantissa.
__device__ __forceinline__ unsigned qenc(float w) {
  unsigned b = __float_as_uint(w);
  int e = 127 - (int)((b >> 23) & 0xFF);
  unsigned m = (b >> 12) & 0x7FFu;
  if (e < 0) { e = 0; m = 0; }
  if (e > 15) { e = 15; m = 0; }
  return ((unsigned)e << 11) | m;
}
__device__ __forceinline__ float qdec(unsigned q) {
  return __uint_as_float(((127u - (q >> 11)) << 23) | ((q & 0x7FFu) << 12));
}

__device__ __forceinline__ float2 uph2(unsigned u) {
  __half2 h = *reinterpret_cast<const __half2*>(&u);
  return __half22float2(h);
}
__device__ __forceinline__ unsigned pkh2(float a, float b) {
  __half2 h = __floats2half2_rn(a, b);
  return *reinterpret_cast<const unsigned*>(&h);
}

// Non-temporal LOADS only (edge lists, staged/adjacency streams). NT STORES
// forbidden (round-7: 6x write amplification on strided stores).
__device__ __forceinline__ int ntli(const int* p) {
  return __builtin_nontemporal_load(p);
}
__device__ __forceinline__ float ntlf(const float* p) {
  return __builtin_nontemporal_load(p);
}
__device__ __forceinline__ long long ntll(const long long* p) {
  return __builtin_nontemporal_load(p);
}
__device__ __forceinline__ void ntsf(float* p, float v) {
  __builtin_nontemporal_store(v, p);   // ONLY for coalesced final output
}

// ---------------------------------------------------------------------------
// Weight prep — all nodeA weights TRANSPOSED so per-wave-uniform rows are
// CONTIGUOUS (batched s_loads). W1t[100][35]; WpackAt[50][40];
// WpackCxt[25][35]; WpackCh[5][25].
// Column maps: A: 0-4 Dz, 5-9 Dr, 10-14 Fz1, 15-19 Fr1, 20-24 Fz2,
// 25-29 Fr2, 30-34 Bz1, 35-39 Br1, 40-44 Bz2, 45-49 Br2.
// C: 0-4 Dh, 5-9 Fh1, 10-14 Fh2, 15-19 Bh1, 20-24 Bh2.
// ---------------------------------------------------------------------------
__global__ __launch_bounds__(256) void prep_weights(
    const float* __restrict__ Wz, const float* __restrict__ Wr,
    const float* __restrict__ Wh, const float* __restrict__ W1,
    float* __restrict__ W1t, float* __restrict__ WpackAt,
    float* __restrict__ WpackCxt, float* __restrict__ WpackCh) {
  int t = blockIdx.x * blockDim.x + threadIdx.x;
  auto W = [&](const float* Wp, int d, int k, int i, int o) {
    return Wp[((d * 3 + k) * 40 + i) * 5 + o];
  };
  auto wa = [&](int i, int c) -> float {
    if (c < 5)  return W(Wz,0,0,i,c)+W(Wz,1,0,i,c)-W(Wz,0,2,i,c)-W(Wz,1,2,i,c);
    if (c < 10) return W(Wr,0,0,i,c-5)+W(Wr,1,0,i,c-5)-W(Wr,0,2,i,c-5)-W(Wr,1,2,i,c-5);
    if (c < 15) return W(Wz,0,1,i,c-10);
    if (c < 20) return W(Wr,0,1,i,c-15);
    if (c < 25) return W(Wz,0,2,i,c-20);
    if (c < 30) return W(Wr,0,2,i,c-25);
    if (c < 35) return W(Wz,1,1,i,c-30);
    if (c < 40) return W(Wr,1,1,i,c-35);
    if (c < 45) return W(Wz,1,2,i,c-40);
    return W(Wr,1,2,i,c-45);
  };
  auto wc = [&](int i, int c) -> float {
    if (c < 5)  return W(Wh,0,0,i,c)+W(Wh,1,0,i,c)-W(Wh,0,2,i,c)-W(Wh,1,2,i,c);
    if (c < 10) return W(Wh,0,1,i,c-5);
    if (c < 15) return W(Wh,0,2,i,c-10);
    if (c < 20) return W(Wh,1,1,i,c-15);
    return W(Wh,1,2,i,c-20);
  };
  if (t < 3500) {                       // W1t[hh][i]
    int hh = t / 35, i = t % 35;
    W1t[t] = W1[i * HID + hh];
  } else if (t < 5500) {                // WpackAt[c][i]
    int u = t - 3500; int c = u / 40, i = u % 40;
    WpackAt[u] = wa(i, c);
  } else if (t < 6375) {                // WpackCxt[c][i], i<35
    int u = t - 5500; int c = u / 35, i = u % 35;
    WpackCxt[u] = wc(i, c);
  } else if (t < 6500) {                // WpackCh[o][c] = wc(35+o, c)
    int u = t - 6375; int o = u / 25, c = u % 25;
    WpackCh[u] = wc(F_IN + o, c);
  }
}

// ---------------------------------------------------------------------------
// Build 1 (passB): LOCAL bucket sort (block-local write window).
// Item: int2{ other | keylow<<17 , 15-bit qweight }.
// ---------------------------------------------------------------------------
__global__ __launch_bounds__(1024) void passB_kernel(
    const int* __restrict__ ei, const float* __restrict__ w,
    int2* __restrict__ staged_f, int2* __restrict__ staged_b,
    int* __restrict__ lomat, int E) {
  __shared__ int hh[MAXB], sc[MAXB], cc[MAXB];
  int dir = blockIdx.y;               // 0: fwd (key=dst), 1: bwd (key=src)
  int j = blockIdx.x;
  int tid = threadIdx.x;
  for (int k = tid; k < MAXB; k += blockDim.x) { hh[k] = 0; cc[k] = 0; }
  __syncthreads();
  size_t c0 = (size_t)j * E / NBLK;
  size_t c1 = (size_t)(j + 1) * E / NBLK;
  const int* keyc = dir ? ei : ei + E;
  const int* othc = dir ? ei + E : ei;
  int2* staged = dir ? staged_b : staged_f;
  int* lom = lomat + ((size_t)dir * NBLK + j) * (MAXB + 1);
  for (size_t e = c0 + tid; e < c1; e += blockDim.x) {
    int key = ntli(keyc + e);
    atomicAdd(&hh[key >> BSH], 1);
  }
  __syncthreads();
  if (tid < MAXB) sc[tid] = hh[tid];
  __syncthreads();
  for (int off = 1; off < MAXB; off <<= 1) {
    int a = (tid >= off && tid < MAXB) ? sc[tid - off] : 0;
    __syncthreads();
    if (tid < MAXB) sc[tid] += a;
    __syncthreads();
  }
  if (tid < MAXB) {
    int lo = sc[tid] - hh[tid];
    lom[tid] = lo;
    hh[tid] = lo;
  }
  if (tid == 0) lom[MAXB] = (int)(c1 - c0);
  __syncthreads();
  for (size_t e = c0 + tid; e < c1; e += blockDim.x) {
    int key = ntli(keyc + e);
    int oth = ntli(othc + e);
    unsigned q = qenc(ntlf(w + e));
    int b = key >> BSH;
    int p = hh[b] + atomicAdd(&cc[b], 1);
    staged[c0 + p] = make_int2(oth | ((key & BMSK) << 17), (int)q);
  }
}

// ---------------------------------------------------------------------------
// Build 2: bucket bases = column sums of lomat count-diffs + exclusive scan.
// ---------------------------------------------------------------------------
__global__ __launch_bounds__(512) void scanb2_kernel(
    const int* __restrict__ lomat,
    int* __restrict__ bbase_f, int* __restrict__ bbase_b,
    int* __restrict__ rs_f, int* __restrict__ rs_b,
    int nbuck, int N, int E) {
  __shared__ int s0[MAXB], s1[MAXB];
  int t = threadIdx.x;
  int cf = 0, cb = 0;
  if (t < nbuck) {
    for (int j = 0; j < NBLK; j++) {
      const int* lf = lomat + (size_t)j * (MAXB + 1);
      const int* lb = lomat + ((size_t)NBLK + j) * (MAXB + 1);
      cf += lf[t + 1] - lf[t];
      cb += lb[t + 1] - lb[t];
    }
  }
  s0[t] = cf; s1[t] = cb;
  __syncthreads();
  for (int off = 1; off < MAXB; off <<= 1) {
    int a = (t >= off) ? s0[t - off] : 0;
    int b = (t >= off) ? s1[t - off] : 0;
    __syncthreads();
    s0[t] += a; s1[t] += b;
    __syncthreads();
  }
  bbase_f[t + 1] = s0[t];
  bbase_b[t + 1] = s1[t];
  if (t == 0) { bbase_f[0] = 0; bbase_b[0] = 0; rs_f[N] = E; rs_b[N] = E; }
}

// ---------------------------------------------------------------------------
// Build 3 (passC): per-bucket CSR finalize, FLAT-INDEXED + SINGLE READ:
// - lbase[129] scan over run lengths; run_of[p] byte table maps positions
//   to runs in O(1)
// - pass 1: flat coalesced loop, items cached in statically-indexed
//   registers (KMAX=20 covers CAPB=5120 >> mean 4096)
// - pass 2: pure register replay (zero global reads); tail >CAPB binary-
//   searches lbase (correctness fallback, never taken for this input)
// dir0 (fwd, keyed by dst) -> inv_in; dir1 (bwd, keyed by src) -> inv_out.
// ---------------------------------------------------------------------------
__global__ __launch_bounds__(256) void passC_kernel(
    const int2* __restrict__ staged_f, const int2* __restrict__ staged_b,
    const int* __restrict__ lomat,
    const int* __restrict__ bbase_f, const int* __restrict__ bbase_b,
    int* __restrict__ adj_f, int* __restrict__ adj_b,
    int* __restrict__ rs_f, int* __restrict__ rs_b,
    float* __restrict__ inv_in, float* __restrict__ inv_out, int N, int E) {
  int dir = blockIdx.y;
  const long long* staged =
      (const long long*)(dir ? staged_b : staged_f);
  const int* lomd = lomat + (size_t)dir * NBLK * (MAXB + 1);
  const int* bbase = dir ? bbase_b : bbase_f;
  int* adj = dir ? adj_b : adj_f;
  int* rs  = dir ? rs_b : rs_f;
  float* inv = dir ? inv_out : inv_in;
  int b = blockIdx.x;
  int base = bbase[b];
  __shared__ int cnt[256]; __shared__ float wsum[256];
  __shared__ int loc[256]; __shared__ int cur[256];
  __shared__ int lbase[NBLK + 1];
  __shared__ int lo0s[NBLK];
  __shared__ int cjs[NBLK];
  __shared__ unsigned char run_of[CAPB];
  int tid = threadIdx.x;
  cnt[tid] = 0; wsum[tid] = 0.f; cur[tid] = 0;
  if (tid < NBLK) {
    const int* lj = lomd + (size_t)tid * (MAXB + 1);
    int lo0 = lj[b], lo1 = lj[b + 1];
    lo0s[tid] = lo0;
    lbase[tid] = lo1 - lo0;
    cjs[tid] = (int)((size_t)tid * E / NBLK);
  }
  __syncthreads();
  // inclusive scan over 128 run lengths
  for (int off = 1; off < NBLK; off <<= 1) {
    int v = (tid < NBLK && tid >= off) ? lbase[tid - off] : 0;
    __syncthreads();
    if (tid < NBLK) lbase[tid] += v;
    __syncthreads();
  }
  int incl = (tid < NBLK) ? lbase[tid] : 0;
  __syncthreads();
  if (tid < NBLK) lbase[tid + 1] = incl;
  if (tid == 0) lbase[0] = 0;
  __syncthreads();
  int total = lbase[NBLK];
  // fill run_of (one thread per run)
  if (tid < NBLK) {
    int p0 = lbase[tid], p1 = lbase[tid + 1];
    int pe = min(p1, CAPB);
    for (int p = p0; p < pe; p++) run_of[p] = (unsigned char)tid;
  }
  __syncthreads();

  // pass 1: flat coalesced loop, cache items in registers
  long long items[KMAX];
  #pragma unroll
  for (int k = 0; k < KMAX; k++) {
    int p = tid + (k << 8);
    if (p < total && p < CAPB) {
      int j = run_of[p];
      int idx = cjs[j] + lo0s[j] + (p - lbase[j]);
      long long it = ntll(staged + idx);
      items[k] = it;
      int idv = (int)(unsigned)(it & 0xFFFFFFFFll);
      unsigned q = (unsigned)((unsigned long long)it >> 32);
      int nl = (idv >> 17) & BMSK;
      atomicAdd(&cnt[nl], 1);
      atomicAdd(&wsum[nl], qdec(q));
    }
  }
  // tail (p >= CAPB): binary search (correctness fallback)
  for (int p = CAPB + tid; p < total; p += 256) {
    int loJ = 0, hiJ = NBLK;
    while (hiJ - loJ > 1) {
      int mid = (loJ + hiJ) >> 1;
      if (lbase[mid] <= p) loJ = mid; else hiJ = mid;
    }
    long long it = ntll(staged + cjs[loJ] + lo0s[loJ] + (p - lbase[loJ]));
    int idv = (int)(unsigned)(it & 0xFFFFFFFFll);
    unsigned q = (unsigned)((unsigned long long)it >> 32);
    int nl = (idv >> 17) & BMSK;
    atomicAdd(&cnt[nl], 1);
    atomicAdd(&wsum[nl], qdec(q));
  }
  __syncthreads();

  // per-node exclusive scan (256 nodes) -> rowstarts + inv degrees
  int v = cnt[tid];
  loc[tid] = v;
  __syncthreads();
  for (int off = 1; off < 256; off <<= 1) {
    int a = (tid >= off) ? loc[tid - off] : 0;
    __syncthreads();
    loc[tid] += a;
    __syncthreads();
  }
  int excl = loc[tid] - v;
  int node = (b << BSH) + tid;
  if (node < N) {
    rs[node] = base + excl;
    inv[node] = 1.f / fmaxf(wsum[tid], 1e-12f);
  }
  __syncthreads();
  loc[tid] = excl;
  __syncthreads();

  // pass 2: register replay (no global reads)
  #pragma unroll
  for (int k = 0; k < KMAX; k++) {
    int p = tid + (k << 8);
    if (p < total && p < CAPB) {
      long long it = items[k];
      int idv = (int)(unsigned)(it & 0xFFFFFFFFll);
      int q = (int)((unsigned long long)it >> 32);
      int nl = (idv >> 17) & BMSK;
      int pos = base + loc[nl] + atomicAdd(&cur[nl], 1);
      adj[pos] = (idv & 0x1FFFF) | (q << 17);
    }
  }
  for (int p = CAPB + tid; p < total; p += 256) {
    int loJ = 0, hiJ = NBLK;
    while (hiJ - loJ > 1) {
      int mid = (loJ + hiJ) >> 1;
      if (lbase[mid] <= p) loJ = mid; else hiJ = mid;
    }
    long long it = ntll(staged + cjs[loJ] + lo0s[loJ] + (p - lbase[loJ]));
    int idv = (int)(unsigned)(it & 0xFFFFFFFFll);
    int q = (int)((unsigned long long)it >> 32);
    int nl = (idv >> 17) & BMSK;
    int pos = base + loc[nl] + atomicAdd(&cur[nl], 1);
    adj[pos] = (idv & 0x1FFFF) | (q << 17);
  }
}

// ---------------------------------------------------------------------------
// Output A: w_fwd = ew * inv_out[src]  (nt store OK: coalesced final output)
// ---------------------------------------------------------------------------
__global__ __launch_bounds__(256) void wfout_kernel(
    const int* __restrict__ ei, const float* __restrict__ ew,
    const float* __restrict__ inv_out, float* __restrict__ wf, int E) {
  for (int e = blockIdx.x * blockDim.x + threadIdx.x; e < E;
       e += gridDim.x * blockDim.x)
    ntsf(wf + e, ntlf(ew + e) * inv_out[ntli(ei + e)]);
}

// ---------------------------------------------------------------------------
// Node phase A: block = 4 waves = 64 nodes; wave-uniform weight indexing
// over TRANSPOSED weights (contiguous rows -> batched s_loads). Plain
// accumulation (round-18's dot4 split-accumulator experiment REGRESSED:
// VGPR 28->48, VALUBusy 33->21% — reverted).
// Emits fp16 PA (p1 gather input, pre-scaled) and fp16 accCx = x@WpackC[0:35].
// ---------------------------------------------------------------------------
__global__ __launch_bounds__(256) void nodeA_kernel(
    const float* __restrict__ x,
    const float* __restrict__ W1t, const float* __restrict__ b1,
    const float* __restrict__ W2, const float* __restrict__ b2,
    const float* __restrict__ bz, const float* __restrict__ br,
    const float* __restrict__ WpackAt, const float* __restrict__ WpackCxt,
    const float* __restrict__ inv_out, const float* __restrict__ inv_in,
    float* __restrict__ h1, float* __restrict__ accDz,
    float* __restrict__ accDr, __half* __restrict__ PA_f,
    __half* __restrict__ PA_b, __half* __restrict__ accCx, int N) {
  __shared__ float part[4][64][5];
  int tid = threadIdx.x;
  int lane = tid & 63;
  int q = __builtin_amdgcn_readfirstlane(tid >> 6);
  int n = blockIdx.x * 64 + lane;
  bool act = n < N;
  float xv[40];
  const float* xr = x + (size_t)n * F_IN;
  #pragma unroll
  for (int i = 0; i < F_IN; i++) xv[i] = act ? xr[i] : 0.f;

  float h5[5] = {0.f, 0.f, 0.f, 0.f, 0.f};
  int hbase = q * 25;
  for (int k = 0; k < 25; k++) {
    int hh = hbase + k;
    const float* w1r = W1t + hh * F_IN;
    float a = b1[hh];
    #pragma unroll
    for (int i = 0; i < F_IN; i++) a = fmaf(xv[i], w1r[i], a);
    a = fmaxf(a, 0.f);
    #pragma unroll
    for (int o = 0; o < 5; o++) h5[o] = fmaf(a, W2[hh * 5 + o], h5[o]);
  }
  #pragma unroll
  for (int o = 0; o < 5; o++) part[q][lane][o] = h5[o];
  __syncthreads();
  #pragma unroll
  for (int o = 0; o < 5; o++) {
    h5[o] = part[0][lane][o] + part[1][lane][o] + part[2][lane][o] +
            part[3][lane][o] + b2[o];
    xv[F_IN + o] = h5[o];
  }
  if (!act) return;
  if (q == 0) {
    #pragma unroll
    for (int o = 0; o < 5; o++) h1[(size_t)n * 5 + o] = h5[o];
  }
  float sOut = inv_out[n], sIn = inv_in[n];
  // 75 columns: 0-49 WpackAt (XH), 50-74 WpackCxt (x only)
  int c0 = q * 19, c1 = min(c0 + 19, 75);
  for (int c = c0; c < c1; c++) {
    float a = 0.f;
    if (c < 50) {
      const float* wr = WpackAt + c * 40;
      #pragma unroll
      for (int i = 0; i < 40; i++) a = fmaf(xv[i], wr[i], a);
    } else {
      const float* wr = WpackCxt + (c - 50) * F_IN;
      #pragma unroll
      for (int i = 0; i < F_IN; i++) a = fmaf(xv[i], wr[i], a);
    }
    if (c < 5)       accDz[(size_t)n * 5 + c] = a + bz[c];
    else if (c < 10) accDr[(size_t)n * 5 + (c - 5)] = a + br[c - 5];
    else if (c < 30) PA_f[(size_t)n * 20 + (c - 10)] = __float2half(a * sOut);
    else if (c < 50) PA_b[(size_t)n * 20 + (c - 30)] = __float2half(a * sIn);
    else             accCx[(size_t)n * 25 + (c - 50)] = __float2half(a);
  }
}

// ---------------------------------------------------------------------------
// P1: 1-hop fwd+bwd. DIR-PER-BLOCK. Paired lanes share (node,dir), 10-col
// halves. 4-wide BATCHED gather loop (overlaps 4 gather latencies).
// half0 -> Q1 fp32; half1 -> Q2 fp16 [N][12] (5+pad groups, pre-scaled).
// ---------------------------------------------------------------------------
__global__ __launch_bounds__(256) void p1_kernel(
    const int* __restrict__ rs_f, const int* __restrict__ rs_b,
    const int* __restrict__ adj_f, const int* __restrict__ adj_b,
    const __half* __restrict__ PA_f, const __half* __restrict__ PA_b,
    const float* __restrict__ inv_out, const float* __restrict__ inv_in,
    float* __restrict__ Q1_f, float* __restrict__ Q1_b,
    __half* __restrict__ Q2_f, __half* __restrict__ Q2_b, int N) {
  int dir = blockIdx.x & 1;
  int idx = (blockIdx.x >> 1) * 256 + threadIdx.x;
  if (idx >= 2 * N) return;
  int n = idx >> 1, half = idx & 1;
  const int* rs  = dir ? rs_b : rs_f;
  const int* adj = dir ? adj_b : adj_f;
  const __half* PA = dir ? PA_b : PA_f;
  int i0 = rs[n], i1 = rs[n + 1];
  float acc[10];
  #pragma unroll
  for (int c = 0; c < 10; c++) acc[c] = 0.f;
  int i = i0;
  for (; i + 4 <= i1; i += 4) {
    int a0 = ntli(adj + i),     a1 = ntli(adj + i + 1),
        a2 = ntli(adj + i + 2), a3 = ntli(adj + i + 3);
    const unsigned* r0 = (const unsigned*)(PA + (size_t)(a0 & 0x1FFFF) * 20) + half * 5;
    const unsigned* r1 = (const unsigned*)(PA + (size_t)(a1 & 0x1FFFF) * 20) + half * 5;
    const unsigned* r2 = (const unsigned*)(PA + (size_t)(a2 & 0x1FFFF) * 20) + half * 5;
    const unsigned* r3 = (const unsigned*)(PA + (size_t)(a3 & 0x1FFFF) * 20) + half * 5;
    unsigned u0[5], u1[5], u2[5], u3[5];
    #pragma unroll
    for (int k = 0; k < 5; k++) u0[k] = r0[k];
    #pragma unroll
    for (int k = 0; k < 5; k++) u1[k] = r1[k];
    #pragma unroll
    for (int k = 0; k < 5; k++) u2[k] = r2[k];
    #pragma unroll
    for (int k = 0; k < 5; k++) u3[k] = r3[k];
    float w0 = qdec(((unsigned)a0) >> 17), w1 = qdec(((unsigned)a1) >> 17),
          w2 = qdec(((unsigned)a2) >> 17), w3 = qdec(((unsigned)a3) >> 17);
    #pragma unroll
    for (int k = 0; k < 5; k++) {
      float2 f0 = uph2(u0[k]), f1 = uph2(u1[k]), f2 = uph2(u2[k]), f3 = uph2(u3[k]);
      acc[2*k]   = fmaf(w0, f0.x, acc[2*k]);   acc[2*k+1] = fmaf(w0, f0.y, acc[2*k+1]);
      acc[2*k]   = fmaf(w1, f1.x, acc[2*k]);   acc[2*k+1] = fmaf(w1, f1.y, acc[2*k+1]);
      acc[2*k]   = fmaf(w2, f2.x, acc[2*k]);   acc[2*k+1] = fmaf(w2, f2.y, acc[2*k+1]);
      acc[2*k]   = fmaf(w3, f3.x, acc[2*k]);   acc[2*k+1] = fmaf(w3, f3.y, acc[2*k+1]);
    }
  }
  for (; i < i1; i++) {
    int a = ntli(adj + i);
    float w = qdec(((unsigned)a) >> 17);
    const unsigned* row = (const unsigned*)(PA + (size_t)(a & 0x1FFFF) * 20) + half * 5;
    #pragma unroll
    for (int k = 0; k < 5; k++) {
      float2 f = uph2(row[k]);
      acc[2*k] = fmaf(w, f.x, acc[2*k]); acc[2*k+1] = fmaf(w, f.y, acc[2*k+1]);
    }
  }
  if (!half) {
    float* q = (dir ? Q1_b : Q1_f) + (size_t)n * 10;
    #pragma unroll
    for (int c = 0; c < 10; c++) q[c] = acc[c];
  } else {
    float sc = dir ? inv_in[n] : inv_out[n];
    unsigned* q = (unsigned*)((dir ? Q2_b : Q2_f) + (size_t)n * 12);
    q[0] = pkh2(acc[0] * sc, acc[1] * sc);
    q[1] = pkh2(acc[2] * sc, acc[3] * sc);
    q[2] = pkh2(acc[4] * sc, 0.f);
    q[3] = pkh2(acc[5] * sc, acc[6] * sc);
    q[4] = pkh2(acc[7] * sc, acc[8] * sc);
    q[5] = pkh2(acc[9] * sc, 0.f);
  }
}

// ---------------------------------------------------------------------------
// P2a: 2-hop gather, DIR-PER-BLOCK (single-dir Q2 = 2.88MB, L2-resident per
// XCD). Paired lanes = (node, group). 8-wide batched gather.
// Writes per-direction partials G[dir][N][10] fp32 (node-local).
// ---------------------------------------------------------------------------
__global__ __launch_bounds__(256) void p2a_kernel(
    const int* __restrict__ rs_f, const int* __restrict__ rs_b,
    const int* __restrict__ adj_f, const int* __restrict__ adj_b,
    const __half* __restrict__ Q2_f, const __half* __restrict__ Q2_b,
    float* __restrict__ G_f, float* __restrict__ G_b, int N) {
  int dir = blockIdx.x & 1;
  int idx = (blockIdx.x >> 1) * 256 + threadIdx.x;
  if (idx >= 2 * N) return;
  int n = idx >> 1, grp = idx & 1;
  const int* rs  = dir ? rs_b : rs_f;
  const int* adj = dir ? adj_b : adj_f;
  const __half* Q2 = dir ? Q2_b : Q2_f;
  int i0 = rs[n], i1 = rs[n + 1];
  float a[5];
  #pragma unroll
  for (int c = 0; c < 5; c++) a[c] = 0.f;
  int i = i0;
  for (; i + 8 <= i1; i += 8) {
    int e[8];
    #pragma unroll
    for (int k = 0; k < 8; k++) e[k] = ntli(adj + i + k);
    unsigned u[8][3];
    #pragma unroll
    for (int k = 0; k < 8; k++) {
      const unsigned* row =
          (const unsigned*)(Q2 + (size_t)(e[k] & 0x1FFFF) * 12) + grp * 3;
      u[k][0] = row[0]; u[k][1] = row[1]; u[k][2] = row[2];
    }
    #pragma unroll
    for (int k = 0; k < 8; k++) {
      float w = qdec(((unsigned)e[k]) >> 17);
      float2 f0 = uph2(u[k][0]), f1 = uph2(u[k][1]), f2 = uph2(u[k][2]);
      a[0] = fmaf(w, f0.x, a[0]); a[1] = fmaf(w, f0.y, a[1]);
      a[2] = fmaf(w, f1.x, a[2]); a[3] = fmaf(w, f1.y, a[3]);
      a[4] = fmaf(w, f2.x, a[4]);
    }
  }
  for (; i < i1; i++) {
    int e = ntli(adj + i);
    float w = qdec(((unsigned)e) >> 17);
    const unsigned* row =
        (const unsigned*)(Q2 + (size_t)(e & 0x1FFFF) * 12) + grp * 3;
    float2 f0 = uph2(row[0]), f1 = uph2(row[1]), f2 = uph2(row[2]);
    a[0] = fmaf(w, f0.x, a[0]); a[1] = fmaf(w, f0.y, a[1]);
    a[2] = fmaf(w, f1.x, a[2]); a[3] = fmaf(w, f1.y, a[3]);
    a[4] = fmaf(w, f2.x, a[4]);
  }
  float* g = (dir ? G_b : G_f) + (size_t)n * 10 + grp * 5;
  #pragma unroll
  for (int c = 0; c < 5; c++) g[c] = a[c];
}

// ---------------------------------------------------------------------------
// P2b: nodeB body (streaming only). zA/rA = G_f + G_b; gates; XHr epilogue
// (accCx precomputed; only the 5 h-rows via WpackCh). 2N threads, columns
// split 13/12 over lane pair.
// ---------------------------------------------------------------------------
__global__ __launch_bounds__(256) void p2b_kernel(
    const float* __restrict__ G_f, const float* __restrict__ G_b,
    const float* __restrict__ Q1_f, const float* __restrict__ Q1_b,
    const float* __restrict__ accDz, const float* __restrict__ accDr,
    const __half* __restrict__ accCx, const float* __restrict__ h1,
    const float* __restrict__ bh, const float* __restrict__ WpackCh,
    const float* __restrict__ inv_out, const float* __restrict__ inv_in,
    float* __restrict__ Zg, float* __restrict__ accDh,
    __half* __restrict__ PH_f, __half* __restrict__ PH_b, int N) {
  int t = blockIdx.x * blockDim.x + threadIdx.x;
  int n = t >> 1, l = t & 1;
  if (n >= N) return;
  float r[5], zv[5];
  #pragma unroll
  for (int o = 0; o < 5; o++) {
    float zA = G_f[(size_t)n * 10 + o] + G_b[(size_t)n * 10 + o];
    float rA = G_f[(size_t)n * 10 + 5 + o] + G_b[(size_t)n * 10 + 5 + o];
    float zp = accDz[(size_t)n * 5 + o] + Q1_f[(size_t)n * 10 + o] +
               Q1_b[(size_t)n * 10 + o] + 2.f * zA;
    float rp = accDr[(size_t)n * 5 + o] + Q1_f[(size_t)n * 10 + 5 + o] +
               Q1_b[(size_t)n * 10 + 5 + o] + 2.f * rA;
    zv[o] = 1.f / (1.f + __expf(-zp));
    r[o]  = 1.f / (1.f + __expf(-rp));
  }
  if (l == 0) {
    #pragma unroll
    for (int o = 0; o < 5; o++) Zg[(size_t)n * 5 + o] = zv[o];
  }
  float hr[5];
  #pragma unroll
  for (int o = 0; o < 5; o++) hr[o] = h1[(size_t)n * 5 + o] * r[o];

  float sOut = inv_out[n], sIn = inv_in[n];
  int c0 = l ? 13 : 0, c1 = l ? 25 : 13;
  for (int c = c0; c < c1; c++) {
    float acc = __half2float(accCx[(size_t)n * 25 + c]);
    #pragma unroll
    for (int o = 0; o < 5; o++) acc = fmaf(hr[o], WpackCh[o * 25 + c], acc);
    if (c < 5)       accDh[(size_t)n * 5 + c] = acc + bh[c];
    else if (c < 10) PH_f[(size_t)n * 12 + (c - 5)] = __float2half(acc * sOut);
    else if (c < 15) PH_f[(size_t)n * 12 + 6 + (c - 10)] = __float2half(acc * sOut);
    else if (c < 20) PH_b[(size_t)n * 12 + (c - 15)] = __float2half(acc * sIn);
    else             PH_b[(size_t)n * 12 + 6 + (c - 20)] = __float2half(acc * sIn);
  }
}

// ---------------------------------------------------------------------------
// P3: 1-hop h, DIR-PER-BLOCK; paired-lane split over PH's two 5-col groups.
// 8-wide batched gather. (h0-4 -> Q1h fp32; h6-10 -> Q2h fp16 pre-scaled.)
// ---------------------------------------------------------------------------
__global__ __launch_bounds__(256) void p3_kernel(
    const int* __restrict__ rs_f, const int* __restrict__ rs_b,
    const int* __restrict__ adj_f, const int* __restrict__ adj_b,
    const __half* __restrict__ PH_f, const __half* __restrict__ PH_b,
    const float* __restrict__ inv_out, const float* __restrict__ inv_in,
    float* __restrict__ Q1h_f, float* __restrict__ Q1h_b,
    __half* __restrict__ Q2h_f, __half* __restrict__ Q2h_b, int N) {
  int dir = blockIdx.x & 1;
  int idx = (blockIdx.x >> 1) * 256 + threadIdx.x;
  if (idx >= 2 * N) return;
  int n = idx >> 1, half = idx & 1;
  const int* rs  = dir ? rs_b : rs_f;
  const int* adj = dir ? adj_b : adj_f;
  const __half* PH = dir ? PH_b : PH_f;
  int i0 = rs[n], i1 = rs[n + 1];
  float acc[5];
  #pragma unroll
  for (int c = 0; c < 5; c++) acc[c] = 0.f;
  int i = i0;
  for (; i + 8 <= i1; i += 8) {
    int e[8];
    #pragma unroll
    for (int k = 0; k < 8; k++) e[k] = ntli(adj + i + k);
    unsigned u[8][3];
    #pragma unroll
    for (int k = 0; k < 8; k++) {
      const unsigned* row =
          (const unsigned*)(PH + (size_t)(e[k] & 0x1FFFF) * 12) + half * 3;
      u[k][0] = row[0]; u[k][1] = row[1]; u[k][2] = row[2];
    }
    #pragma unroll
    for (int k = 0; k < 8; k++) {
      float w = qdec(((unsigned)e[k]) >> 17);
      float2 f0 = uph2(u[k][0]), f1 = uph2(u[k][1]), f2 = uph2(u[k][2]);
      acc[0] = fmaf(w, f0.x, acc[0]); acc[1] = fmaf(w, f0.y, acc[1]);
      acc[2] = fmaf(w, f1.x, acc[2]); acc[3] = fmaf(w, f1.y, acc[3]);
      acc[4] = fmaf(w, f2.x, acc[4]);
    }
  }
  for (; i < i1; i++) {
    int a = ntli(adj + i);
    float w = qdec(((unsigned)a) >> 17);
    const unsigned* row =
        (const unsigned*)(PH + (size_t)(a & 0x1FFFF) * 12) + half * 3;
    float2 f0 = uph2(row[0]), f1 = uph2(row[1]), f2 = uph2(row[2]);
    acc[0] = fmaf(w, f0.x, acc[0]); acc[1] = fmaf(w, f0.y, acc[1]);
    acc[2] = fmaf(w, f1.x, acc[2]); acc[3] = fmaf(w, f1.y, acc[3]);
    acc[4] = fmaf(w, f2.x, acc[4]);
  }
  if (!half) {
    float* q = (dir ? Q1h_b : Q1h_f) + (size_t)n * 5;
    #pragma unroll
    for (int c = 0; c < 5; c++) q[c] = acc[c];
  } else {
    float sc = dir ? inv_in[n] : inv_out[n];
    unsigned* q = (unsigned*)((dir ? Q2h_b : Q2h_f) + (size_t)n * 8);
    q[0] = pkh2(acc[0] * sc, acc[1] * sc);
    q[1] = pkh2(acc[2] * sc, acc[3] * sc);
    q[2] = pkh2(acc[4] * sc, 0.f);
  }
}

// ---------------------------------------------------------------------------
// P4: 2-hop h gather (fp16 Q2h, lane dir-split, 8-wide batched) + nodeC -> y.
// ---------------------------------------------------------------------------
__global__ __launch_bounds__(256) void p4_kernel(
    const int* __restrict__ rs_f, const int* __restrict__ rs_b,
    const int* __restrict__ adj_f, const int* __restrict__ adj_b,
    const __half* __restrict__ Q2h_f, const __half* __restrict__ Q2h_b,
    const float* __restrict__ Q1h_f, const float* __restrict__ Q1h_b,
    const float* __restrict__ accDh, const float* __restrict__ Zg,
    const float* __restrict__ h1, const float* __restrict__ Wl,
    const float* __restrict__ bl, float* __restrict__ y, int N) {
  int t = blockIdx.x * blockDim.x + threadIdx.x;
  int n = t >> 1, l = t & 1;
  if (n >= N) return;
  const int* rs  = l ? rs_b : rs_f;
  const int* adj = l ? adj_b : adj_f;
  const __half* Q2h = l ? Q2h_b : Q2h_f;
  float a[5];
  #pragma unroll
  for (int c = 0; c < 5; c++) a[c] = 0.f;
  int i0 = rs[n], i1 = rs[n + 1];
  int i = i0;
  for (; i + 8 <= i1; i += 8) {
    int e[8];
    #pragma unroll
    for (int k = 0; k < 8; k++) e[k] = ntli(adj + i + k);
    unsigned u[8][3];
    #pragma unroll
    for (int k = 0; k < 8; k++) {
      const unsigned* row = (const unsigned*)(Q2h + (size_t)(e[k] & 0x1FFFF) * 8);
      u[k][0] = row[0]; u[k][1] = row[1]; u[k][2] = row[2];
    }
    #pragma unroll
    for (int k = 0; k < 8; k++) {
      float w = qdec(((unsigned)e[k]) >> 17);
      float2 f0 = uph2(u[k][0]), f1 = uph2(u[k][1]), f2 = uph2(u[k][2]);
      a[0] = fmaf(w, f0.x, a[0]); a[1] = fmaf(w, f0.y, a[1]);
      a[2] = fmaf(w, f1.x, a[2]); a[3] = fmaf(w, f1.y, a[3]);
      a[4] = fmaf(w, f2.x, a[4]);
    }
  }
  for (; i < i1; i++) {
    int e = ntli(adj + i);
    float w = qdec(((unsigned)e) >> 17);
    const unsigned* row = (const unsigned*)(Q2h + (size_t)(e & 0x1FFFF) * 8);
    float2 f0 = uph2(row[0]), f1 = uph2(row[1]), f2 = uph2(row[2]);
    a[0] = fmaf(w, f0.x, a[0]); a[1] = fmaf(w, f0.y, a[1]);
    a[2] = fmaf(w, f1.x, a[2]); a[3] = fmaf(w, f1.y, a[3]);
    a[4] = fmaf(w, f2.x, a[4]);
  }
  #pragma unroll
  for (int c = 0; c < 5; c++) a[c] += __shfl_xor(a[c], 1);
  if (l) return;
  float acc = bl[0];
  #pragma unroll
  for (int o = 0; o < 5; o++) {
    float pre = accDh[(size_t)n * 5 + o] + Q1h_f[(size_t)n * 5 + o] +
                Q1h_b[(size_t)n * 5 + o] + 2.f * a[o];
    float ht = tanhf(pre);
    float z = Zg[(size_t)n * 5 + o];
    float H = z * h1[(size_t)n * 5 + o] + (1.f - z) * ht;
    acc += fmaxf(H, 0.f) * Wl[o];
  }
  y[n] = acc;
}

// ---------------------------------------------------------------------------
extern "C" void kernel_launch(void* const* d_in, const int* in_sizes, int n_in,
                              void* d_out, int out_size, void* d_ws, size_t ws_size,
                              hipStream_t stream) {
  const float* x  = (const float*)d_in[0];
  const int*   ei = (const int*)d_in[1];
  const float* ew = (const float*)d_in[2];
  const float* W1 = (const float*)d_in[3];
  const float* b1 = (const float*)d_in[4];
  const float* W2 = (const float*)d_in[5];
  const float* b2 = (const float*)d_in[6];
  const float* Wz = (const float*)d_in[7];
  const float* bz = (const float*)d_in[8];
  const float* Wr = (const float*)d_in[9];
  const float* br = (const float*)d_in[10];
  const float* Wh = (const float*)d_in[11];
  const float* bh = (const float*)d_in[12];
  const float* Wl = (const float*)d_in[13];
  const float* bl = (const float*)d_in[14];

  const int N = in_sizes[0] / F_IN;
  const int E = in_sizes[2];
  const int nbuck = ((N - 1) >> BSH) + 1;   // N <= 131072 assumed

  float* out = (float*)d_out;
  float* y_out  = out;          // [N]
  float* wf_out = out + N;      // [E]  == output A

  // Workspace layout (4-byte words; 8B alignment maintained for packed loads)
  float* W = (float*)d_ws;
  size_t o = 0;
  int* bbase_f = (int*)(W + o); o += MAXB + 2;
  int* bbase_b = (int*)(W + o); o += MAXB + 2;
  int* lomat   = (int*)(W + o); o += (size_t)2 * NBLK * (MAXB + 1);
  int* rs_f    = (int*)(W + o); o += (size_t)N + 1;
  int* rs_b    = (int*)(W + o); o += (size_t)N + 1;
  float* inv_out = W + o; o += N;
  float* inv_in  = W + o; o += N;
  int* adj_f   = (int*)(W + o); o += (size_t)E;
  int* adj_b   = (int*)(W + o); o += (size_t)E;
  float* h1    = W + o; o += (size_t)5 * N;
  float* accDz = W + o; o += (size_t)5 * N;
  float* accDr = W + o; o += (size_t)5 * N;
  float* accDh = W + o; o += (size_t)5 * N;
  float* Zg    = W + o; o += (size_t)5 * N;
  __half* accCx = (__half*)(W + o); o += (size_t)13 * N;  // [N][25] fp16
  o = (o + 1) & ~(size_t)1;                 // 8B align
  size_t prop0 = o;                         // staged aliases from here
  __half* PA_f = (__half*)(W + o); o += (size_t)10 * N;   // [N][20] fp16
  __half* PA_b = (__half*)(W + o); o += (size_t)10 * N;
  float* Q1_f  = W + o; o += (size_t)10 * N;              // [N][10] fp32
  float* Q1_b  = W + o; o += (size_t)10 * N;
  __half* Q2_f = (__half*)(W + o); o += (size_t)6 * N;    // [N][12] fp16
  __half* Q2_b = (__half*)(W + o); o += (size_t)6 * N;
  __half* PH_f = (__half*)(W + o); o += (size_t)6 * N;    // [N][12] fp16
  __half* PH_b = (__half*)(W + o); o += (size_t)6 * N;
  float* Q1h_f = W + o; o += (size_t)5 * N;               // [N][5] fp32
  float* Q1h_b = W + o; o += (size_t)5 * N;
  o = (o + 1) & ~(size_t)1;
  __half* Q2h_f = (__half*)(W + o); o += (size_t)4 * N;   // [N][8] fp16
  __half* Q2h_b = (__half*)(W + o); o += (size_t)4 * N;
  float* G_f   = W + o; o += (size_t)10 * N;              // [N][10] fp32
  float* G_b   = W + o; o += (size_t)10 * N;
  float* W1t     = W + o; o += 3500;                      // [100][35]
  float* WpackAt = W + o; o += 2000;                      // [50][40]
  float* WpackCxt = W + o; o += 875;                      // [25][35]
  float* WpackCh  = W + o; o += 125;                      // [5][25]

  // staged scratch aliases the prop region (consumed by passC before nodeA
  // writes anything there); needs 4E words <= prop-region words (~102N).
  int2* staged_f = (int2*)(W + prop0);
  int2* staged_b = staged_f + E;

  const int NB2 = (2 * N + 255) / 256;
  const int NBd = 2 * ((2 * N + 255) / 256);   // dir-per-block grids
  const int NBn = (N + 63) / 64;

  // 1. packed/transposed weights (6500 work items)
  prep_weights<<<26, 256, 0, stream>>>(Wz, Wr, Wh, W1,
                                       W1t, WpackAt, WpackCxt, WpackCh);

  // 2. CSR build: local sort -> bucket-base scan -> per-bucket finalize
  passB_kernel<<<dim3(NBLK, 2), 1024, 0, stream>>>(ei, ew, staged_f, staged_b,
                                                   lomat, E);
  scanb2_kernel<<<1, MAXB, 0, stream>>>(lomat, bbase_f, bbase_b,
                                        rs_f, rs_b, nbuck, N, E);
  passC_kernel<<<dim3(nbuck, 2), 256, 0, stream>>>(
      staged_f, staged_b, lomat, bbase_f, bbase_b, adj_f, adj_b,
      rs_f, rs_b, inv_in, inv_out, N, E);
  wfout_kernel<<<1024, 256, 0, stream>>>(ei, ew, inv_out, wf_out, E);

  // 3. node phase A (transposed weights)
  nodeA_kernel<<<NBn, 256, 0, stream>>>(x, W1t, b1, W2, b2, bz, br, WpackAt,
                                        WpackCxt, inv_out, inv_in,
                                        h1, accDz, accDr, PA_f, PA_b,
                                        accCx, N);

  // 4. fused propagation + gate phases
  p1_kernel<<<NBd, 256, 0, stream>>>(rs_f, rs_b, adj_f, adj_b, PA_f, PA_b,
                                     inv_out, inv_in, Q1_f, Q1_b, Q2_f, Q2_b, N);
  p2a_kernel<<<NBd, 256, 0, stream>>>(rs_f, rs_b, adj_f, adj_b, Q2_f, Q2_b,
                                      G_f, G_b, N);
  p2b_kernel<<<NB2, 256, 0, stream>>>(G_f, G_b, Q1_f, Q1_b, accDz, accDr,
                                      accCx, h1, bh, WpackCh, inv_out, inv_in,
                                      Zg, accDh, PH_f, PH_b, N);
  p3_kernel<<<NBd, 256, 0, stream>>>(rs_f, rs_b, adj_f, adj_b, PH_f, PH_b,
                                     inv_out, inv_in, Q1h_f, Q1h_b,
                                     Q2h_f, Q2h_b, N);
  p4_kernel<<<NB2, 256, 0, stream>>>(rs_f, rs_b, adj_f, adj_b, Q2h_f, Q2h_b,
                                     Q1h_f, Q1h_b, accDh, Zg, h1, Wl, bl,
                                     y_out, N);
}